// Round 18
// baseline (64.098 us; speedup 1.0000x reference)
//
#include <hip/hip_runtime.h>
#include <math.h>

#define NSEQ   1024
#define HEADS  8
#define DHEAD  64
#define SCALE  0.125f
#define LOG2E  1.4426950408889634f

typedef unsigned int u32;
typedef unsigned short u16;
typedef short short8 __attribute__((ext_vector_type(8)));   // 8 bf16 (4 VGPRs)
typedef __bf16 bf16x2 __attribute__((ext_vector_type(2)));
typedef __bf16 bf16x8 __attribute__((ext_vector_type(8)));
typedef float f32x4  __attribute__((ext_vector_type(4)));
typedef float f32x16 __attribute__((ext_vector_type(16)));

__device__ __forceinline__ u16 f2bf(float f) {
    __bf16 h = (__bf16)f;
    return __builtin_bit_cast(u16, h);
}
__device__ __forceinline__ u32 pk2(float lo, float hi) {
    bf16x2 v; v[0] = (__bf16)lo; v[1] = (__bf16)hi;
    return __builtin_bit_cast(u32, v);
}
__device__ __forceinline__ float bf2f(u16 b) {
    u32 u = ((u32)b) << 16;
    return __builtin_bit_cast(float, u);
}
// no inline-asm exp (R6 lesson: unscheduled TRANS hazard -> nondeterminism)
__device__ __forceinline__ float exp2_fast(float x) {
#if __has_builtin(__builtin_amdgcn_exp2f)
    return __builtin_amdgcn_exp2f(x);
#else
    return exp2f(x);
#endif
}
__device__ __forceinline__ f32x4 mfma16(short8 a, short8 b, f32x4 c) {
    return __builtin_amdgcn_mfma_f32_16x16x32_bf16(a, b, c, 0, 0, 0);
}
__device__ __forceinline__ f32x16 mfma32(short8 a, short8 b, f32x16 c) {
    return __builtin_amdgcn_mfma_f32_32x32x16_bf16(a, b, c, 0, 0, 0);
}

// ---------------------------------------------------------------------------
// prep (R15-exact): x->bf16 convert + both weight transpose-converts.
// blocks [0,1024): conv x; [1024,1216): w_qkv^T; [1216,1280): w_out^T.
// ---------------------------------------------------------------------------
__global__ __launch_bounds__(256) void prep(const float* __restrict__ x,
                                            const float* __restrict__ wqkv,
                                            const float* __restrict__ wout,
                                            u16* __restrict__ x_bf,
                                            u16* __restrict__ wqkvT,
                                            u16* __restrict__ woutT) {
    __shared__ float T[64][65];
    const int t = threadIdx.x;
    const int bb = blockIdx.x;
    if (bb < 1024) {
        int i = (bb * 256 + t) * 8;
        float4 a = *(const float4*)&x[i];
        float4 b = *(const float4*)&x[i + 4];
        bf16x8 v;
        v[0] = (__bf16)a.x; v[1] = (__bf16)a.y; v[2] = (__bf16)a.z; v[3] = (__bf16)a.w;
        v[4] = (__bf16)b.x; v[5] = (__bf16)b.y; v[6] = (__bf16)b.z; v[7] = (__bf16)b.w;
        *(short8*)&x_bf[i] = __builtin_bit_cast(short8, v);
        return;
    }
    const float* in; u16* outp; int K, N, n0, k0;
    if (bb < 1216) {
        int bid = bb - 1024;
        in = wqkv; outp = wqkvT; K = 512; N = 1536;
        n0 = (bid % 24) * 64; k0 = (bid / 24) * 64;
    } else {
        int bid = bb - 1216;
        in = wout; outp = woutT; K = 512; N = 512;
        n0 = (bid % 8) * 64; k0 = (bid / 8) * 64;
    }
    #pragma unroll
    for (int rep = 0; rep < 4; ++rep) {
        int r = rep * 16 + (t >> 4), c = (t & 15) * 4;
        float4 v = *(const float4*)&in[(size_t)(k0 + r) * N + n0 + c];
        T[r][c + 0] = v.x; T[r][c + 1] = v.y; T[r][c + 2] = v.z; T[r][c + 3] = v.w;
    }
    __syncthreads();
    const int nl = t >> 2, kb = (t & 3) * 16;
    bf16x8 s0, s1;
    #pragma unroll
    for (int e = 0; e < 8; ++e) s0[e] = (__bf16)T[kb + e][nl];
    #pragma unroll
    for (int e = 0; e < 8; ++e) s1[e] = (__bf16)T[kb + 8 + e][nl];
    *(short8*)&outp[(size_t)(n0 + nl) * K + k0 + kb]     = __builtin_bit_cast(short8, s0);
    *(short8*)&outp[(size_t)(n0 + nl) * K + k0 + kb + 8] = __builtin_bit_cast(short8, s1);
}

// ---------------------------------------------------------------------------
// GEMM qkv (R15-exact): BM=128 x BN=64, BK=64, 1D grid 768 XCD-chunked.
// v path writes C^T -> vT[b,h,d,n].
// ---------------------------------------------------------------------------
__global__ __launch_bounds__(256) void gemm_qkv_mfma(const u16* __restrict__ xb,
                                                     const u16* __restrict__ wT,
                                                     u16* __restrict__ qb,
                                                     u16* __restrict__ kb,
                                                     u16* __restrict__ vT) {
    __shared__ u16 As[128][72];
    __shared__ u16 Bs[64][72];
    const int t = threadIdx.x, lane = t & 63, w = t >> 6;
    const int wm = w >> 1, wn = w & 1;
    const int l15 = lane & 15, l4 = lane >> 4;
    const int bid = blockIdx.x;
    const int swz = (bid & 7) * 96 + (bid >> 3);      // 768 = 8*96, bijective
    const int j0 = (swz % 24) * 64, i0 = (swz / 24) * 128;
    const int which = j0 / 512;           // 0=q 1=k 2=v (uniform per block)
    const int b = i0 >> 10;

    f32x4 acc[8];
    #pragma unroll
    for (int i = 0; i < 8; ++i) acc[i] = (f32x4){0.f, 0.f, 0.f, 0.f};

    const int arow0 = t >> 2, c16 = (t & 3) * 16;

    short8 ra[4], rb2[2];
    #pragma unroll
    for (int rep = 0; rep < 2; ++rep)
        #pragma unroll
        for (int q = 0; q < 2; ++q)
            ra[rep * 2 + q] = *(const short8*)&xb[(size_t)(i0 + rep * 64 + arow0) * 512 + c16 + q * 8];
    #pragma unroll
    for (int q = 0; q < 2; ++q)
        rb2[q] = *(const short8*)&wT[(size_t)(j0 + arow0) * 512 + c16 + q * 8];

    for (int kt = 0; kt < 8; ++kt) {
        __syncthreads();
        #pragma unroll
        for (int rep = 0; rep < 2; ++rep)
            #pragma unroll
            for (int q = 0; q < 2; ++q)
                *(short8*)&As[rep * 64 + arow0][c16 + q * 8] = ra[rep * 2 + q];
        #pragma unroll
        for (int q = 0; q < 2; ++q)
            *(short8*)&Bs[arow0][c16 + q * 8] = rb2[q];
        __syncthreads();
        if (kt < 7) {
            int k0 = (kt + 1) * 64;
            #pragma unroll
            for (int rep = 0; rep < 2; ++rep)
                #pragma unroll
                for (int q = 0; q < 2; ++q)
                    ra[rep * 2 + q] = *(const short8*)&xb[(size_t)(i0 + rep * 64 + arow0) * 512 + k0 + c16 + q * 8];
            #pragma unroll
            for (int q = 0; q < 2; ++q)
                rb2[q] = *(const short8*)&wT[(size_t)(j0 + arow0) * 512 + k0 + c16 + q * 8];
        }
        #pragma unroll
        for (int ks = 0; ks < 2; ++ks) {
            if (which < 2) {
                short8 af[4], bf[2];
                #pragma unroll
                for (int m = 0; m < 4; ++m)
                    af[m] = *(const short8*)&As[wm * 64 + m * 16 + l15][ks * 32 + l4 * 8];
                #pragma unroll
                for (int n = 0; n < 2; ++n)
                    bf[n] = *(const short8*)&Bs[wn * 32 + n * 16 + l15][ks * 32 + l4 * 8];
                #pragma unroll
                for (int m = 0; m < 4; ++m)
                    #pragma unroll
                    for (int n = 0; n < 2; ++n)
                        acc[m * 2 + n] = mfma16(af[m], bf[n], acc[m * 2 + n]);
            } else {
                short8 af[2], bf[4];
                #pragma unroll
                for (int mj = 0; mj < 2; ++mj)
                    af[mj] = *(const short8*)&Bs[wn * 32 + mj * 16 + l15][ks * 32 + l4 * 8];
                #pragma unroll
                for (int ni = 0; ni < 4; ++ni)
                    bf[ni] = *(const short8*)&As[wm * 64 + ni * 16 + l15][ks * 32 + l4 * 8];
                #pragma unroll
                for (int mj = 0; mj < 2; ++mj)
                    #pragma unroll
                    for (int ni = 0; ni < 4; ++ni)
                        acc[mj * 4 + ni] = mfma16(af[mj], bf[ni], acc[mj * 4 + ni]);
            }
        }
    }

    if (which < 2) {
        u16* dst = (which == 0) ? qb : kb;
        const int h = (j0 & 511) >> 6;
        #pragma unroll
        for (int m = 0; m < 4; ++m)
            #pragma unroll
            for (int n = 0; n < 2; ++n) {
                int d = wn * 32 + n * 16 + l15;
                #pragma unroll
                for (int r = 0; r < 4; ++r) {
                    int tok = i0 + wm * 64 + m * 16 + l4 * 4 + r;
                    dst[(((size_t)(b * HEADS + h)) * NSEQ + (tok & 1023)) * DHEAD + d] =
                        f2bf(acc[m * 2 + n][r]);
                }
            }
    } else {
        const int h = (j0 - 1024) >> 6;
        #pragma unroll
        for (int mj = 0; mj < 2; ++mj)
            #pragma unroll
            for (int ni = 0; ni < 4; ++ni) {
                int tok = i0 + wm * 64 + ni * 16 + l15;
                #pragma unroll
                for (int r = 0; r < 4; ++r) {
                    int d = wn * 32 + mj * 16 + l4 * 4 + r;
                    vT[(((size_t)(b * HEADS + h)) * DHEAD + d) * NSEQ + (tok & 1023)] =
                        f2bf(acc[mj * 4 + ni][r]);
                }
            }
    }
}

// ---------------------------------------------------------------------------
// Flash attention v7: R15 + 3-deep prefetch.  Two named reg sets (A=even
// tiles, B=odd tiles); loads for tile jt+3 issue at iteration jt, staged at
// jt+2, consumed at jt+3 -> 2 tiles in flight, ~2 compute periods of latency
// cover.  launch_bounds(256,1): grid=256 is 1 block/CU anyway; give the
// allocator the full VGPR file (~280 regs needed, 512 budget).
// ---------------------------------------------------------------------------
__global__ __launch_bounds__(256, 1) void attn_mfma(const u16* __restrict__ qb,
                                                    const u16* __restrict__ kb,
                                                    const u16* __restrict__ vT,
                                                    const float* __restrict__ spd,
                                                    const float* __restrict__ head_keep,
                                                    u16* __restrict__ ab) {
    __shared__ u16 Kd[2][64][72];
    __shared__ u16 Vd[2][64][72];
    __shared__ u16 Sd[2][128][66];   // bf16 spd * log2e

    const int t = threadIdx.x, lane = t & 63, w = t >> 6;
    const int hi = lane >> 5, li = lane & 31;
    const int bid = blockIdx.x;
    const int swz = (bid & 7) * 32 + (bid >> 3);   // 256 = 8*32, bijective
    const int bh = swz >> 3, it = swz & 7;
    const int b = bh >> 3, h = bh & 7;
    const int i0 = it * 128;

    const u16* qh = qb + (size_t)bh * NSEQ * DHEAD;
    const u16* kh = kb + (size_t)bh * NSEQ * DHEAD;
    const u16* vh = vT + (size_t)bh * DHEAD * NSEQ;
    const float* sp = spd + (size_t)bh * NSEQ * NSEQ;

    // Q fragments in registers
    short8 qreg[4];
    #pragma unroll
    for (int ds = 0; ds < 4; ++ds)
        qreg[ds] = *(const short8*)&qh[(size_t)(i0 + w * 32 + li) * DHEAD + ds * 16 + hi * 8];

    const int krow = t >> 3, kc8 = (t & 7) * 8;
    const int srow = t >> 4, sc = (t & 15) * 4;

    short8 kA[2], vA[2], kB[2], vB[2];
    float4 sA[8], sB[8];

    // ---- prologue: stage tile0 via setA; issue tile1->B, tile2->A ----
    #pragma unroll
    for (int rep = 0; rep < 2; ++rep) {
        kA[rep] = *(const short8*)&kh[(size_t)(rep * 32 + krow) * DHEAD + kc8];
        vA[rep] = *(const short8*)&vh[(size_t)(rep * 32 + krow) * NSEQ + kc8];
    }
    #pragma unroll
    for (int rep = 0; rep < 8; ++rep)
        sA[rep] = *(const float4*)&sp[(size_t)(i0 + rep * 16 + srow) * NSEQ + sc];
    #pragma unroll
    for (int rep = 0; rep < 2; ++rep) {
        *(short8*)&Kd[0][rep * 32 + krow][kc8] = kA[rep];
        *(short8*)&Vd[0][rep * 32 + krow][kc8] = vA[rep];
    }
    #pragma unroll
    for (int rep = 0; rep < 8; ++rep) {
        int rrow = rep * 16 + srow;
        *(u32*)&Sd[0][rrow][sc]     = pk2(sA[rep].x * LOG2E, sA[rep].y * LOG2E);
        *(u32*)&Sd[0][rrow][sc + 2] = pk2(sA[rep].z * LOG2E, sA[rep].w * LOG2E);
    }
    #pragma unroll
    for (int rep = 0; rep < 2; ++rep) {
        kB[rep] = *(const short8*)&kh[(size_t)(64 + rep * 32 + krow) * DHEAD + kc8];
        vB[rep] = *(const short8*)&vh[(size_t)(rep * 32 + krow) * NSEQ + 64 + kc8];
    }
    #pragma unroll
    for (int rep = 0; rep < 8; ++rep)
        sB[rep] = *(const float4*)&sp[(size_t)(i0 + rep * 16 + srow) * NSEQ + 64 + sc];
    #pragma unroll
    for (int rep = 0; rep < 2; ++rep) {
        kA[rep] = *(const short8*)&kh[(size_t)(128 + rep * 32 + krow) * DHEAD + kc8];
        vA[rep] = *(const short8*)&vh[(size_t)(rep * 32 + krow) * NSEQ + 128 + kc8];
    }
    #pragma unroll
    for (int rep = 0; rep < 8; ++rep)
        sA[rep] = *(const float4*)&sp[(size_t)(i0 + rep * 16 + srow) * NSEQ + 128 + sc];
    __syncthreads();

    float m_s = -1e30f, l_s = 0.f;
    f32x16 o0 = {}, o1 = {};
    #pragma unroll
    for (int r = 0; r < 16; ++r) { o0[r] = 0.f; o1[r] = 0.f; }

    // STEP(JT, set): compute tile JT; stage tile JT+1 from `set`; issue
    // tile JT+3 into `set`; one barrier.  set parity = (JT+1)&1.
#define ATTN_STEP(JT, RK, RV, RS)                                             \
    {                                                                         \
        const int cur = (JT) & 1;                                             \
        f32x16 s2[2];                                                         \
        _Pragma("unroll")                                                     \
        for (int kg = 0; kg < 2; ++kg) {                                      \
            _Pragma("unroll")                                                 \
            for (int r = 0; r < 16; ++r) s2[kg][r] = 0.f;                     \
            _Pragma("unroll")                                                 \
            for (int ds = 0; ds < 4; ++ds) {                                  \
                short8 ak = *(const short8*)&Kd[cur][kg * 32 + li][ds * 16 + hi * 8]; \
                s2[kg] = mfma32(ak, qreg[ds], s2[kg]);                        \
            }                                                                 \
        }                                                                     \
        float p2[32];                                                         \
        _Pragma("unroll")                                                     \
        for (int kg = 0; kg < 2; ++kg)                                        \
            _Pragma("unroll")                                                 \
            for (int r = 0; r < 16; ++r) {                                    \
                int key = kg * 32 + (r & 3) + 8 * (r >> 2) + 4 * hi;          \
                p2[kg * 16 + r] = fmaf(s2[kg][r], SCALE * LOG2E,              \
                                       bf2f(Sd[cur][w * 32 + li][key]));      \
            }                                                                 \
        float m16[16];                                                        \
        _Pragma("unroll")                                                     \
        for (int r = 0; r < 16; ++r) m16[r] = fmaxf(p2[r], p2[r + 16]);       \
        float m8v[8];                                                         \
        _Pragma("unroll")                                                     \
        for (int r = 0; r < 8; ++r) m8v[r] = fmaxf(m16[r], m16[r + 8]);       \
        float m4v[4];                                                         \
        _Pragma("unroll")                                                     \
        for (int r = 0; r < 4; ++r) m4v[r] = fmaxf(m8v[r], m8v[r + 4]);       \
        float pmax = fmaxf(fmaxf(m4v[0], m4v[1]), fmaxf(m4v[2], m4v[3]));     \
        pmax = fmaxf(pmax, __shfl_xor(pmax, 32));                             \
        if (!__all(pmax <= m_s + 12.0f)) {                                    \
            float mnew = fmaxf(m_s, pmax);                                    \
            float fac = exp2_fast(m_s - mnew);                                \
            m_s = mnew;                                                       \
            l_s *= fac;                                                       \
            _Pragma("unroll")                                                 \
            for (int r = 0; r < 16; ++r) {                                    \
                int ip = (r & 3) + 8 * (r >> 2) + 4 * hi;                     \
                float fr = __shfl(fac, ip);                                   \
                o0[r] *= fr; o1[r] *= fr;                                     \
            }                                                                 \
        }                                                                     \
        float sa0 = 0.f, sa1 = 0.f, sa2 = 0.f, sa3 = 0.f;                     \
        _Pragma("unroll")                                                     \
        for (int r = 0; r < 32; r += 4) {                                     \
            p2[r + 0] = exp2_fast(p2[r + 0] - m_s); sa0 += p2[r + 0];         \
            p2[r + 1] = exp2_fast(p2[r + 1] - m_s); sa1 += p2[r + 1];         \
            p2[r + 2] = exp2_fast(p2[r + 2] - m_s); sa2 += p2[r + 2];         \
            p2[r + 3] = exp2_fast(p2[r + 3] - m_s); sa3 += p2[r + 3];         \
        }                                                                     \
        float rsum = (sa0 + sa1) + (sa2 + sa3);                               \
        rsum += __shfl_xor(rsum, 32);                                         \
        l_s += rsum;                                                          \
        short8 pf[4];                                                         \
        _Pragma("unroll")                                                     \
        for (int ks = 0; ks < 4; ++ks) {                                      \
            int rb = (ks >> 1) * 16 + (ks & 1) * 8;                           \
            u32 a0 = pk2(p2[rb + 0], p2[rb + 1]);                             \
            u32 a1 = pk2(p2[rb + 2], p2[rb + 3]);                             \
            u32 a2 = pk2(p2[rb + 4], p2[rb + 5]);                             \
            u32 a3 = pk2(p2[rb + 6], p2[rb + 7]);                             \
            u32 x0 = (u32)__shfl_xor((int)a0, 32);                            \
            u32 x1 = (u32)__shfl_xor((int)a1, 32);                            \
            u32 x2 = (u32)__shfl_xor((int)a2, 32);                            \
            u32 x3 = (u32)__shfl_xor((int)a3, 32);                            \
            union { u32 u[4]; short8 v; } c4;                                 \
            c4.u[0] = hi ? x2 : a0;                                           \
            c4.u[1] = hi ? x3 : a1;                                           \
            c4.u[2] = hi ? a2 : x0;                                           \
            c4.u[3] = hi ? a3 : x1;                                           \
            pf[ks] = c4.v;                                                    \
        }                                                                     \
        _Pragma("unroll")                                                     \
        for (int ks = 0; ks < 4; ++ks) {                                      \
            short8 v0f = *(const short8*)&Vd[cur][li][ks * 16 + hi * 8];      \
            short8 v1f = *(const short8*)&Vd[cur][32 + li][ks * 16 + hi * 8]; \
            o0 = mfma32(pf[ks], v0f, o0);                                     \
            o1 = mfma32(pf[ks], v1f, o1);                                     \
        }                                                                     \
        if ((JT) < 15) {                                                      \
            const int nxt = cur ^ 1;                                          \
            _Pragma("unroll")                                                 \
            for (int rep = 0; rep < 2; ++rep) {                               \
                *(short8*)&Kd[nxt][rep * 32 + krow][kc8] = RK[rep];           \
                *(short8*)&Vd[nxt][rep * 32 + krow][kc8] = RV[rep];           \
            }                                                                 \
            _Pragma("unroll")                                                 \
            for (int rep = 0; rep < 8; ++rep) {                               \
                int rrow = rep * 16 + srow;                                   \
                *(u32*)&Sd[nxt][rrow][sc]     = pk2(RS[rep].x * LOG2E, RS[rep].y * LOG2E); \
                *(u32*)&Sd[nxt][rrow][sc + 2] = pk2(RS[rep].z * LOG2E, RS[rep].w * LOG2E); \
            }                                                                 \
            if ((JT) < 13) {                                                  \
                int j0n = ((JT) + 3) * 64;                                    \
                _Pragma("unroll")                                             \
                for (int rep = 0; rep < 2; ++rep) {                           \
                    RK[rep] = *(const short8*)&kh[(size_t)(j0n + rep * 32 + krow) * DHEAD + kc8]; \
                    RV[rep] = *(const short8*)&vh[(size_t)(rep * 32 + krow) * NSEQ + j0n + kc8];  \
                }                                                             \
                _Pragma("unroll")                                             \
                for (int rep = 0; rep < 8; ++rep)                             \
                    RS[rep] = *(const float4*)&sp[(size_t)(i0 + rep * 16 + srow) * NSEQ + j0n + sc]; \
            }                                                                 \
            __syncthreads();                                                  \
        }                                                                     \
    }

    for (int jt2 = 0; jt2 < 16; jt2 += 2) {
        ATTN_STEP(jt2,     kB, vB, sB)   // stage tile jt2+1 (odd -> setB)
        ATTN_STEP(jt2 + 1, kA, vA, sA)   // stage tile jt2+2 (even -> setA)
    }
#undef ATTN_STEP

    // epilogue
    float ksum = 0.f;
    #pragma unroll
    for (int i = 0; i < HEADS; ++i) ksum += head_keep[i];
    const float hscale = head_keep[h] * (float)HEADS / ksum;
    const float inv = hscale / l_s;
    #pragma unroll
    for (int r = 0; r < 16; ++r) {
        int ip = (r & 3) + 8 * (r >> 2) + 4 * hi;
        float invr = __shfl(inv, ip);
        int tok = i0 + w * 32 + ip;
        size_t base = ((size_t)(b * NSEQ) + tok) * 512 + h * DHEAD;
        ab[base + li]      = f2bf(o0[r] * invr);
        ab[base + 32 + li] = f2bf(o1[r] * invr);
    }
}

// ---------------------------------------------------------------------------
// GEMM out (R15-exact): BM=64 x BN=64, BK=64, 1D grid 512 XCD-chunked.
// ---------------------------------------------------------------------------
__global__ __launch_bounds__(256) void gemm_out_mfma(const u16* __restrict__ abuf,
                                                     const u16* __restrict__ wT,
                                                     const float* __restrict__ bias,
                                                     float* __restrict__ out) {
    __shared__ u16 As[64][72];
    __shared__ u16 Bs[64][72];
    const int t = threadIdx.x, lane = t & 63, w = t >> 6;
    const int wm = w >> 1, wn = w & 1;
    const int l15 = lane & 15, l4 = lane >> 4;
    const int bid = blockIdx.x;
    const int swz = (bid & 7) * 64 + (bid >> 3);      // 512 = 8*64, bijective
    const int j0 = (swz % 8) * 64, i0 = (swz / 8) * 64;

    f32x4 acc[2][2];
    #pragma unroll
    for (int m = 0; m < 2; ++m)
        #pragma unroll
        for (int n = 0; n < 2; ++n) acc[m][n] = (f32x4){0.f, 0.f, 0.f, 0.f};

    const int row0 = t >> 2, c16 = (t & 3) * 16;
    short8 rav[2], rbv[2];
    #pragma unroll
    for (int q = 0; q < 2; ++q) {
        rav[q] = *(const short8*)&abuf[(size_t)(i0 + row0) * 512 + c16 + q * 8];
        rbv[q] = *(const short8*)&wT[(size_t)(j0 + row0) * 512 + c16 + q * 8];
    }

    for (int kt = 0; kt < 8; ++kt) {
        __syncthreads();
        #pragma unroll
        for (int q = 0; q < 2; ++q) {
            *(short8*)&As[row0][c16 + q * 8] = rav[q];
            *(short8*)&Bs[row0][c16 + q * 8] = rbv[q];
        }
        __syncthreads();
        if (kt < 7) {
            int k0 = (kt + 1) * 64;
            #pragma unroll
            for (int q = 0; q < 2; ++q) {
                rav[q] = *(const short8*)&abuf[(size_t)(i0 + row0) * 512 + k0 + c16 + q * 8];
                rbv[q] = *(const short8*)&wT[(size_t)(j0 + row0) * 512 + k0 + c16 + q * 8];
            }
        }
        #pragma unroll
        for (int ks = 0; ks < 2; ++ks) {
            short8 af[2], bf[2];
            #pragma unroll
            for (int m = 0; m < 2; ++m)
                af[m] = *(const short8*)&As[wm * 32 + m * 16 + l15][ks * 32 + l4 * 8];
            #pragma unroll
            for (int n = 0; n < 2; ++n)
                bf[n] = *(const short8*)&Bs[wn * 32 + n * 16 + l15][ks * 32 + l4 * 8];
            #pragma unroll
            for (int m = 0; m < 2; ++m)
                #pragma unroll
                for (int n = 0; n < 2; ++n)
                    acc[m][n] = mfma16(af[m], bf[n], acc[m][n]);
        }
    }

    #pragma unroll
    for (int m = 0; m < 2; ++m)
        #pragma unroll
        for (int n = 0; n < 2; ++n) {
            int col = j0 + wn * 32 + n * 16 + l15;
            float bb = bias[col];
            #pragma unroll
            for (int r = 0; r < 4; ++r) {
                int row = i0 + wm * 32 + m * 16 + l4 * 4 + r;
                out[(size_t)row * 512 + col] = acc[m][n][r] + bb;
            }
        }
}

extern "C" void kernel_launch(void* const* d_in, const int* in_sizes, int n_in,
                              void* d_out, int out_size, void* d_ws, size_t ws_size,
                              hipStream_t stream) {
    const float* x         = (const float*)d_in[0];
    const float* spd       = (const float*)d_in[1];
    const float* head_keep = (const float*)d_in[2];
    const float* w_qkv     = (const float*)d_in[3];
    const float* w_out     = (const float*)d_in[4];
    const float* b_out     = (const float*)d_in[5];
    float* out = (float*)d_out;

    char* ws = (char*)d_ws;
    u16* x_bf   = (u16*)(ws);                       // 4096*512
    u16* wqkvT  = (u16*)(ws + (4u << 20));          // 1536*512
    u16* woutT  = (u16*)(ws + (4u << 20) + 1572864);// 512*512
    u16* qb     = (u16*)(ws + (6u << 20));          // 32*1024*64
    u16* kb     = (u16*)(ws + (10u << 20));
    u16* vT     = (u16*)(ws + (14u << 20));
    u16* ab     = (u16*)(ws + (18u << 20));         // 4096*512

    prep<<<1280, 256, 0, stream>>>(x, w_qkv, w_out, x_bf, wqkvT, woutT);
    gemm_qkv_mfma<<<768, 256, 0, stream>>>(x_bf, wqkvT, qb, kb, vT);
    attn_mfma<<<256, 256, 0, stream>>>(qb, kb, vT, spd, head_keep, ab);
    gemm_out_mfma<<<512, 256, 0, stream>>>(ab, woutT, b_out, out);
}

// Round 21
// 62.554 us; speedup vs baseline: 1.0247x; 1.0247x over previous
//
#include <hip/hip_runtime.h>
#include <math.h>

#define NSEQ   1024
#define HEADS  8
#define DHEAD  64
#define SCALE  0.125f
#define LOG2E  1.4426950408889634f

typedef unsigned int u32;
typedef unsigned short u16;
typedef short short8 __attribute__((ext_vector_type(8)));   // 8 bf16 (4 VGPRs)
typedef __bf16 bf16x2 __attribute__((ext_vector_type(2)));
typedef __bf16 bf16x8 __attribute__((ext_vector_type(8)));
typedef float f32x4  __attribute__((ext_vector_type(4)));
typedef float f32x16 __attribute__((ext_vector_type(16)));

__device__ __forceinline__ u16 f2bf(float f) {
    __bf16 h = (__bf16)f;
    return __builtin_bit_cast(u16, h);
}
__device__ __forceinline__ u32 pk2(float lo, float hi) {
    bf16x2 v; v[0] = (__bf16)lo; v[1] = (__bf16)hi;
    return __builtin_bit_cast(u32, v);
}
__device__ __forceinline__ float bf2f(u16 b) {
    u32 u = ((u32)b) << 16;
    return __builtin_bit_cast(float, u);
}
// no inline-asm exp (R6 lesson: unscheduled TRANS hazard -> nondeterminism)
__device__ __forceinline__ float exp2_fast(float x) {
#if __has_builtin(__builtin_amdgcn_exp2f)
    return __builtin_amdgcn_exp2f(x);
#else
    return exp2f(x);
#endif
}
__device__ __forceinline__ f32x4 mfma16(short8 a, short8 b, f32x4 c) {
    return __builtin_amdgcn_mfma_f32_16x16x32_bf16(a, b, c, 0, 0, 0);
}
__device__ __forceinline__ f32x16 mfma32(short8 a, short8 b, f32x16 c) {
    return __builtin_amdgcn_mfma_f32_32x32x16_bf16(a, b, c, 0, 0, 0);
}

// ---------------------------------------------------------------------------
// prep (R15-exact): x->bf16 convert + both weight transpose-converts.
// blocks [0,1024): conv x; [1024,1216): w_qkv^T; [1216,1280): w_out^T.
// ---------------------------------------------------------------------------
__global__ __launch_bounds__(256) void prep(const float* __restrict__ x,
                                            const float* __restrict__ wqkv,
                                            const float* __restrict__ wout,
                                            u16* __restrict__ x_bf,
                                            u16* __restrict__ wqkvT,
                                            u16* __restrict__ woutT) {
    __shared__ float T[64][65];
    const int t = threadIdx.x;
    const int bb = blockIdx.x;
    if (bb < 1024) {
        int i = (bb * 256 + t) * 8;
        float4 a = *(const float4*)&x[i];
        float4 b = *(const float4*)&x[i + 4];
        bf16x8 v;
        v[0] = (__bf16)a.x; v[1] = (__bf16)a.y; v[2] = (__bf16)a.z; v[3] = (__bf16)a.w;
        v[4] = (__bf16)b.x; v[5] = (__bf16)b.y; v[6] = (__bf16)b.z; v[7] = (__bf16)b.w;
        *(short8*)&x_bf[i] = __builtin_bit_cast(short8, v);
        return;
    }
    const float* in; u16* outp; int K, N, n0, k0;
    if (bb < 1216) {
        int bid = bb - 1024;
        in = wqkv; outp = wqkvT; K = 512; N = 1536;
        n0 = (bid % 24) * 64; k0 = (bid / 24) * 64;
    } else {
        int bid = bb - 1216;
        in = wout; outp = woutT; K = 512; N = 512;
        n0 = (bid % 8) * 64; k0 = (bid / 8) * 64;
    }
    #pragma unroll
    for (int rep = 0; rep < 4; ++rep) {
        int r = rep * 16 + (t >> 4), c = (t & 15) * 4;
        float4 v = *(const float4*)&in[(size_t)(k0 + r) * N + n0 + c];
        T[r][c + 0] = v.x; T[r][c + 1] = v.y; T[r][c + 2] = v.z; T[r][c + 3] = v.w;
    }
    __syncthreads();
    const int nl = t >> 2, kb = (t & 3) * 16;
    bf16x8 s0, s1;
    #pragma unroll
    for (int e = 0; e < 8; ++e) s0[e] = (__bf16)T[kb + e][nl];
    #pragma unroll
    for (int e = 0; e < 8; ++e) s1[e] = (__bf16)T[kb + 8 + e][nl];
    *(short8*)&outp[(size_t)(n0 + nl) * K + k0 + kb]     = __builtin_bit_cast(short8, s0);
    *(short8*)&outp[(size_t)(n0 + nl) * K + k0 + kb + 8] = __builtin_bit_cast(short8, s1);
}

// ---------------------------------------------------------------------------
// GEMM qkv (R15-exact): BM=128 x BN=64, BK=64, 1D grid 768 XCD-chunked.
// v path writes C^T -> vT[b,h,d,n].
// ---------------------------------------------------------------------------
__global__ __launch_bounds__(256) void gemm_qkv_mfma(const u16* __restrict__ xb,
                                                     const u16* __restrict__ wT,
                                                     u16* __restrict__ qb,
                                                     u16* __restrict__ kb,
                                                     u16* __restrict__ vT) {
    __shared__ u16 As[128][72];
    __shared__ u16 Bs[64][72];
    const int t = threadIdx.x, lane = t & 63, w = t >> 6;
    const int wm = w >> 1, wn = w & 1;
    const int l15 = lane & 15, l4 = lane >> 4;
    const int bid = blockIdx.x;
    const int swz = (bid & 7) * 96 + (bid >> 3);      // 768 = 8*96, bijective
    const int j0 = (swz % 24) * 64, i0 = (swz / 24) * 128;
    const int which = j0 / 512;           // 0=q 1=k 2=v (uniform per block)
    const int b = i0 >> 10;

    f32x4 acc[8];
    #pragma unroll
    for (int i = 0; i < 8; ++i) acc[i] = (f32x4){0.f, 0.f, 0.f, 0.f};

    const int arow0 = t >> 2, c16 = (t & 3) * 16;

    short8 ra[4], rb2[2];
    #pragma unroll
    for (int rep = 0; rep < 2; ++rep)
        #pragma unroll
        for (int q = 0; q < 2; ++q)
            ra[rep * 2 + q] = *(const short8*)&xb[(size_t)(i0 + rep * 64 + arow0) * 512 + c16 + q * 8];
    #pragma unroll
    for (int q = 0; q < 2; ++q)
        rb2[q] = *(const short8*)&wT[(size_t)(j0 + arow0) * 512 + c16 + q * 8];

    for (int kt = 0; kt < 8; ++kt) {
        __syncthreads();
        #pragma unroll
        for (int rep = 0; rep < 2; ++rep)
            #pragma unroll
            for (int q = 0; q < 2; ++q)
                *(short8*)&As[rep * 64 + arow0][c16 + q * 8] = ra[rep * 2 + q];
        #pragma unroll
        for (int q = 0; q < 2; ++q)
            *(short8*)&Bs[arow0][c16 + q * 8] = rb2[q];
        __syncthreads();
        if (kt < 7) {
            int k0 = (kt + 1) * 64;
            #pragma unroll
            for (int rep = 0; rep < 2; ++rep)
                #pragma unroll
                for (int q = 0; q < 2; ++q)
                    ra[rep * 2 + q] = *(const short8*)&xb[(size_t)(i0 + rep * 64 + arow0) * 512 + k0 + c16 + q * 8];
            #pragma unroll
            for (int q = 0; q < 2; ++q)
                rb2[q] = *(const short8*)&wT[(size_t)(j0 + arow0) * 512 + k0 + c16 + q * 8];
        }
        #pragma unroll
        for (int ks = 0; ks < 2; ++ks) {
            if (which < 2) {
                short8 af[4], bf[2];
                #pragma unroll
                for (int m = 0; m < 4; ++m)
                    af[m] = *(const short8*)&As[wm * 64 + m * 16 + l15][ks * 32 + l4 * 8];
                #pragma unroll
                for (int n = 0; n < 2; ++n)
                    bf[n] = *(const short8*)&Bs[wn * 32 + n * 16 + l15][ks * 32 + l4 * 8];
                #pragma unroll
                for (int m = 0; m < 4; ++m)
                    #pragma unroll
                    for (int n = 0; n < 2; ++n)
                        acc[m * 2 + n] = mfma16(af[m], bf[n], acc[m * 2 + n]);
            } else {
                short8 af[2], bf[4];
                #pragma unroll
                for (int mj = 0; mj < 2; ++mj)
                    af[mj] = *(const short8*)&Bs[wn * 32 + mj * 16 + l15][ks * 32 + l4 * 8];
                #pragma unroll
                for (int ni = 0; ni < 4; ++ni)
                    bf[ni] = *(const short8*)&As[wm * 64 + ni * 16 + l15][ks * 32 + l4 * 8];
                #pragma unroll
                for (int mj = 0; mj < 2; ++mj)
                    #pragma unroll
                    for (int ni = 0; ni < 4; ++ni)
                        acc[mj * 4 + ni] = mfma16(af[mj], bf[ni], acc[mj * 4 + ni]);
            }
        }
    }

    if (which < 2) {
        u16* dst = (which == 0) ? qb : kb;
        const int h = (j0 & 511) >> 6;
        #pragma unroll
        for (int m = 0; m < 4; ++m)
            #pragma unroll
            for (int n = 0; n < 2; ++n) {
                int d = wn * 32 + n * 16 + l15;
                #pragma unroll
                for (int r = 0; r < 4; ++r) {
                    int tok = i0 + wm * 64 + m * 16 + l4 * 4 + r;
                    dst[(((size_t)(b * HEADS + h)) * NSEQ + (tok & 1023)) * DHEAD + d] =
                        f2bf(acc[m * 2 + n][r]);
                }
            }
    } else {
        const int h = (j0 - 1024) >> 6;
        #pragma unroll
        for (int mj = 0; mj < 2; ++mj)
            #pragma unroll
            for (int ni = 0; ni < 4; ++ni) {
                int tok = i0 + wm * 64 + ni * 16 + l15;
                #pragma unroll
                for (int r = 0; r < 4; ++r) {
                    int d = wn * 32 + mj * 16 + l4 * 4 + r;
                    vT[(((size_t)(b * HEADS + h)) * DHEAD + d) * NSEQ + (tok & 1023)] =
                        f2bf(acc[mj * 4 + ni][r]);
                }
            }
    }
}

// ---------------------------------------------------------------------------
// Flash attention v8 = R15 pipeline (double-buffered, 1 barrier/jt, Q-reg,
// bf16 Sd) + NEW coalesced epilogue: O staged bf16 into retired Kd LDS
// (128x72, 16B-aligned rows), then 4 contiguous short8 global stores per
// thread instead of 32 scalar 2B stores.
// ---------------------------------------------------------------------------
__global__ __launch_bounds__(256, 2) void attn_mfma(const u16* __restrict__ qb,
                                                    const u16* __restrict__ kb,
                                                    const u16* __restrict__ vT,
                                                    const float* __restrict__ spd,
                                                    const float* __restrict__ head_keep,
                                                    u16* __restrict__ ab) {
    __shared__ u16 Kd[2][64][72];
    __shared__ u16 Vd[2][64][72];
    __shared__ u16 Sd[2][128][66];   // bf16 spd * log2e

    const int t = threadIdx.x, lane = t & 63, w = t >> 6;
    const int hi = lane >> 5, li = lane & 31;
    const int bid = blockIdx.x;
    const int swz = (bid & 7) * 32 + (bid >> 3);   // 256 = 8*32, bijective
    const int bh = swz >> 3, it = swz & 7;
    const int b = bh >> 3, h = bh & 7;
    const int i0 = it * 128;

    const u16* qh = qb + (size_t)bh * NSEQ * DHEAD;
    const u16* kh = kb + (size_t)bh * NSEQ * DHEAD;
    const u16* vh = vT + (size_t)bh * DHEAD * NSEQ;
    const float* sp = spd + (size_t)bh * NSEQ * NSEQ;

    // Q fragments in registers: lane (w,hi,li) needs row w*32+li only.
    short8 qreg[4];
    #pragma unroll
    for (int ds = 0; ds < 4; ++ds)
        qreg[ds] = *(const short8*)&qh[(size_t)(i0 + w * 32 + li) * DHEAD + ds * 16 + hi * 8];

    const int krow = t >> 3, kc8 = (t & 7) * 8;
    const int srow = t >> 4, sc = (t & 15) * 4;

    short8 rk[2], rv[2];
    float4 rs[8];
    // tile 0 load + stage into buf0
    #pragma unroll
    for (int rep = 0; rep < 2; ++rep) {
        rk[rep] = *(const short8*)&kh[(size_t)(rep * 32 + krow) * DHEAD + kc8];
        rv[rep] = *(const short8*)&vh[(size_t)(rep * 32 + krow) * NSEQ + kc8];
    }
    #pragma unroll
    for (int rep = 0; rep < 8; ++rep)
        rs[rep] = *(const float4*)&sp[(size_t)(i0 + rep * 16 + srow) * NSEQ + sc];
    #pragma unroll
    for (int rep = 0; rep < 2; ++rep) {
        *(short8*)&Kd[0][rep * 32 + krow][kc8] = rk[rep];
        *(short8*)&Vd[0][rep * 32 + krow][kc8] = rv[rep];
    }
    #pragma unroll
    for (int rep = 0; rep < 8; ++rep) {
        int rrow = rep * 16 + srow;
        *(u32*)&Sd[0][rrow][sc]     = pk2(rs[rep].x * LOG2E, rs[rep].y * LOG2E);
        *(u32*)&Sd[0][rrow][sc + 2] = pk2(rs[rep].z * LOG2E, rs[rep].w * LOG2E);
    }
    // issue tile-1 loads (fly across the barrier and iteration-0 compute)
    #pragma unroll
    for (int rep = 0; rep < 2; ++rep) {
        rk[rep] = *(const short8*)&kh[(size_t)(64 + rep * 32 + krow) * DHEAD + kc8];
        rv[rep] = *(const short8*)&vh[(size_t)(rep * 32 + krow) * NSEQ + 64 + kc8];
    }
    #pragma unroll
    for (int rep = 0; rep < 8; ++rep)
        rs[rep] = *(const float4*)&sp[(size_t)(i0 + rep * 16 + srow) * NSEQ + 64 + sc];
    __syncthreads();

    float m_s = -1e30f, l_s = 0.f;
    f32x16 o0 = {}, o1 = {};
    #pragma unroll
    for (int r = 0; r < 16; ++r) { o0[r] = 0.f; o1[r] = 0.f; }

    for (int jt = 0; jt < 16; ++jt) {
        const int cur = jt & 1;

        // ---- compute tile jt from buf[cur] ----
        f32x16 s2[2];
        #pragma unroll
        for (int kg = 0; kg < 2; ++kg) {
            #pragma unroll
            for (int r = 0; r < 16; ++r) s2[kg][r] = 0.f;
            #pragma unroll
            for (int ds = 0; ds < 4; ++ds) {
                short8 ak = *(const short8*)&Kd[cur][kg * 32 + li][ds * 16 + hi * 8];
                s2[kg] = mfma32(ak, qreg[ds], s2[kg]);
            }
        }

        float p2[32];
        #pragma unroll
        for (int kg = 0; kg < 2; ++kg)
            #pragma unroll
            for (int r = 0; r < 16; ++r) {
                int key = kg * 32 + (r & 3) + 8 * (r >> 2) + 4 * hi;
                p2[kg * 16 + r] = fmaf(s2[kg][r], SCALE * LOG2E,
                                       bf2f(Sd[cur][w * 32 + li][key]));
            }
        float m16[16];
        #pragma unroll
        for (int r = 0; r < 16; ++r) m16[r] = fmaxf(p2[r], p2[r + 16]);
        float m8v[8];
        #pragma unroll
        for (int r = 0; r < 8; ++r) m8v[r] = fmaxf(m16[r], m16[r + 8]);
        float m4v[4];
        #pragma unroll
        for (int r = 0; r < 4; ++r) m4v[r] = fmaxf(m8v[r], m8v[r + 4]);
        float pmax = fmaxf(fmaxf(m4v[0], m4v[1]), fmaxf(m4v[2], m4v[3]));
        pmax = fmaxf(pmax, __shfl_xor(pmax, 32));

        if (!__all(pmax <= m_s + 12.0f)) {
            float mnew = fmaxf(m_s, pmax);
            float fac = exp2_fast(m_s - mnew);
            m_s = mnew;
            l_s *= fac;
            #pragma unroll
            for (int r = 0; r < 16; ++r) {
                int ip = (r & 3) + 8 * (r >> 2) + 4 * hi;
                float fr = __shfl(fac, ip);
                o0[r] *= fr; o1[r] *= fr;
            }
        }

        float sa0 = 0.f, sa1 = 0.f, sa2 = 0.f, sa3 = 0.f;
        #pragma unroll
        for (int r = 0; r < 32; r += 4) {
            p2[r + 0] = exp2_fast(p2[r + 0] - m_s); sa0 += p2[r + 0];
            p2[r + 1] = exp2_fast(p2[r + 1] - m_s); sa1 += p2[r + 1];
            p2[r + 2] = exp2_fast(p2[r + 2] - m_s); sa2 += p2[r + 2];
            p2[r + 3] = exp2_fast(p2[r + 3] - m_s); sa3 += p2[r + 3];
        }
        float rsum = (sa0 + sa1) + (sa2 + sa3);
        rsum += __shfl_xor(rsum, 32);
        l_s += rsum;

        short8 pf[4];
        #pragma unroll
        for (int ks = 0; ks < 4; ++ks) {
            int rb = (ks >> 1) * 16 + (ks & 1) * 8;
            u32 a0 = pk2(p2[rb + 0], p2[rb + 1]);
            u32 a1 = pk2(p2[rb + 2], p2[rb + 3]);
            u32 a2 = pk2(p2[rb + 4], p2[rb + 5]);
            u32 a3 = pk2(p2[rb + 6], p2[rb + 7]);
            u32 x0 = (u32)__shfl_xor((int)a0, 32);
            u32 x1 = (u32)__shfl_xor((int)a1, 32);
            u32 x2 = (u32)__shfl_xor((int)a2, 32);
            u32 x3 = (u32)__shfl_xor((int)a3, 32);
            union { u32 u[4]; short8 v; } c4;
            c4.u[0] = hi ? x2 : a0;
            c4.u[1] = hi ? x3 : a1;
            c4.u[2] = hi ? a2 : x0;
            c4.u[3] = hi ? a3 : x1;
            pf[ks] = c4.v;
        }

        #pragma unroll
        for (int ks = 0; ks < 4; ++ks) {
            short8 v0f = *(const short8*)&Vd[cur][li][ks * 16 + hi * 8];
            short8 v1f = *(const short8*)&Vd[cur][32 + li][ks * 16 + hi * 8];
            o0 = mfma32(pf[ks], v0f, o0);
            o1 = mfma32(pf[ks], v1f, o1);
        }

        // ---- stage tile jt+1 into buf[cur^1]; issue tile jt+2 loads ----
        if (jt < 15) {
            const int nxt = cur ^ 1;
            #pragma unroll
            for (int rep = 0; rep < 2; ++rep) {
                *(short8*)&Kd[nxt][rep * 32 + krow][kc8] = rk[rep];
                *(short8*)&Vd[nxt][rep * 32 + krow][kc8] = rv[rep];
            }
            #pragma unroll
            for (int rep = 0; rep < 8; ++rep) {
                int rrow = rep * 16 + srow;
                *(u32*)&Sd[nxt][rrow][sc]     = pk2(rs[rep].x * LOG2E, rs[rep].y * LOG2E);
                *(u32*)&Sd[nxt][rrow][sc + 2] = pk2(rs[rep].z * LOG2E, rs[rep].w * LOG2E);
            }
            if (jt < 14) {
                int j0n = (jt + 2) * 64;
                #pragma unroll
                for (int rep = 0; rep < 2; ++rep) {
                    rk[rep] = *(const short8*)&kh[(size_t)(j0n + rep * 32 + krow) * DHEAD + kc8];
                    rv[rep] = *(const short8*)&vh[(size_t)(rep * 32 + krow) * NSEQ + j0n + kc8];
                }
                #pragma unroll
                for (int rep = 0; rep < 8; ++rep)
                    rs[rep] = *(const float4*)&sp[(size_t)(i0 + rep * 16 + srow) * NSEQ + j0n + sc];
            }
            __syncthreads();
        }
    }

    // ---- epilogue: stage O (bf16, scaled) into retired Kd LDS, then
    // coalesced short8 global stores ----
    float ksum = 0.f;
    #pragma unroll
    for (int i = 0; i < HEADS; ++i) ksum += head_keep[i];
    const float hscale = head_keep[h] * (float)HEADS / ksum;
    const float inv = hscale / l_s;

    u16* Ob = &Kd[0][0][0];          // reuse: 128 rows x 72 u16 (16B-aligned)
    __syncthreads();                 // all waves done reading Kd/Vd/Sd
    #pragma unroll
    for (int r = 0; r < 16; ++r) {
        int ip = (r & 3) + 8 * (r >> 2) + 4 * hi;
        float invr = __shfl(inv, ip);
        int row = w * 32 + ip;
        Ob[row * 72 + li]      = f2bf(o0[r] * invr);
        Ob[row * 72 + 32 + li] = f2bf(o1[r] * invr);
    }
    __syncthreads();
    {
        const int row = t >> 1, half = t & 1;
        size_t base = ((size_t)(b * NSEQ) + i0 + row) * 512 + h * DHEAD + half * 32;
        #pragma unroll
        for (int e = 0; e < 4; ++e)
            *(short8*)&ab[base + e * 8] =
                *(const short8*)&Ob[row * 72 + half * 32 + e * 8];
    }
}

// ---------------------------------------------------------------------------
// GEMM out (R15-exact): BM=64 x BN=64, BK=64, 1D grid 512 XCD-chunked.
// ---------------------------------------------------------------------------
__global__ __launch_bounds__(256) void gemm_out_mfma(const u16* __restrict__ abuf,
                                                     const u16* __restrict__ wT,
                                                     const float* __restrict__ bias,
                                                     float* __restrict__ out) {
    __shared__ u16 As[64][72];
    __shared__ u16 Bs[64][72];
    const int t = threadIdx.x, lane = t & 63, w = t >> 6;
    const int wm = w >> 1, wn = w & 1;
    const int l15 = lane & 15, l4 = lane >> 4;
    const int bid = blockIdx.x;
    const int swz = (bid & 7) * 64 + (bid >> 3);      // 512 = 8*64, bijective
    const int j0 = (swz % 8) * 64, i0 = (swz / 8) * 64;

    f32x4 acc[2][2];
    #pragma unroll
    for (int m = 0; m < 2; ++m)
        #pragma unroll
        for (int n = 0; n < 2; ++n) acc[m][n] = (f32x4){0.f, 0.f, 0.f, 0.f};

    const int row0 = t >> 2, c16 = (t & 3) * 16;
    short8 rav[2], rbv[2];
    #pragma unroll
    for (int q = 0; q < 2; ++q) {
        rav[q] = *(const short8*)&abuf[(size_t)(i0 + row0) * 512 + c16 + q * 8];
        rbv[q] = *(const short8*)&wT[(size_t)(j0 + row0) * 512 + c16 + q * 8];
    }

    for (int kt = 0; kt < 8; ++kt) {
        __syncthreads();
        #pragma unroll
        for (int q = 0; q < 2; ++q) {
            *(short8*)&As[row0][c16 + q * 8] = rav[q];
            *(short8*)&Bs[row0][c16 + q * 8] = rbv[q];
        }
        __syncthreads();
        if (kt < 7) {
            int k0 = (kt + 1) * 64;
            #pragma unroll
            for (int q = 0; q < 2; ++q) {
                rav[q] = *(const short8*)&abuf[(size_t)(i0 + row0) * 512 + k0 + c16 + q * 8];
                rbv[q] = *(const short8*)&wT[(size_t)(j0 + row0) * 512 + k0 + c16 + q * 8];
            }
        }
        #pragma unroll
        for (int ks = 0; ks < 2; ++ks) {
            short8 af[2], bf[2];
            #pragma unroll
            for (int m = 0; m < 2; ++m)
                af[m] = *(const short8*)&As[wm * 32 + m * 16 + l15][ks * 32 + l4 * 8];
            #pragma unroll
            for (int n = 0; n < 2; ++n)
                bf[n] = *(const short8*)&Bs[wn * 32 + n * 16 + l15][ks * 32 + l4 * 8];
            #pragma unroll
            for (int m = 0; m < 2; ++m)
                #pragma unroll
                for (int n = 0; n < 2; ++n)
                    acc[m][n] = mfma16(af[m], bf[n], acc[m][n]);
        }
    }

    #pragma unroll
    for (int m = 0; m < 2; ++m)
        #pragma unroll
        for (int n = 0; n < 2; ++n) {
            int col = j0 + wn * 32 + n * 16 + l15;
            float bb = bias[col];
            #pragma unroll
            for (int r = 0; r < 4; ++r) {
                int row = i0 + wm * 32 + m * 16 + l4 * 4 + r;
                out[(size_t)row * 512 + col] = acc[m][n][r] + bb;
            }
        }
}

extern "C" void kernel_launch(void* const* d_in, const int* in_sizes, int n_in,
                              void* d_out, int out_size, void* d_ws, size_t ws_size,
                              hipStream_t stream) {
    const float* x         = (const float*)d_in[0];
    const float* spd       = (const float*)d_in[1];
    const float* head_keep = (const float*)d_in[2];
    const float* w_qkv     = (const float*)d_in[3];
    const float* w_out     = (const float*)d_in[4];
    const float* b_out     = (const float*)d_in[5];
    float* out = (float*)d_out;

    char* ws = (char*)d_ws;
    u16* x_bf   = (u16*)(ws);                       // 4096*512
    u16* wqkvT  = (u16*)(ws + (4u << 20));          // 1536*512
    u16* woutT  = (u16*)(ws + (4u << 20) + 1572864);// 512*512
    u16* qb     = (u16*)(ws + (6u << 20));          // 32*1024*64
    u16* kb     = (u16*)(ws + (10u << 20));
    u16* vT     = (u16*)(ws + (14u << 20));
    u16* ab     = (u16*)(ws + (18u << 20));         // 4096*512

    prep<<<1280, 256, 0, stream>>>(x, w_qkv, w_out, x_bf, wqkvT, woutT);
    gemm_qkv_mfma<<<768, 256, 0, stream>>>(x_bf, wqkvT, qb, kb, vT);
    attn_mfma<<<256, 256, 0, stream>>>(qb, kb, vT, spd, head_keep, ab);
    gemm_out_mfma<<<512, 256, 0, stream>>>(ab, woutT, b_out, out);
}

// Round 22
// 61.687 us; speedup vs baseline: 1.0391x; 1.0141x over previous
//
#include <hip/hip_runtime.h>
#include <math.h>

#define NSEQ   1024
#define HEADS  8
#define DHEAD  64
#define SCALE  0.125f
#define LOG2E  1.4426950408889634f

typedef unsigned int u32;
typedef unsigned short u16;
typedef short short8 __attribute__((ext_vector_type(8)));   // 8 bf16 (4 VGPRs)
typedef __bf16 bf16x2 __attribute__((ext_vector_type(2)));
typedef __bf16 bf16x8 __attribute__((ext_vector_type(8)));
typedef float f32x4  __attribute__((ext_vector_type(4)));
typedef float f32x16 __attribute__((ext_vector_type(16)));

__device__ __forceinline__ u16 f2bf(float f) {
    __bf16 h = (__bf16)f;
    return __builtin_bit_cast(u16, h);
}
__device__ __forceinline__ u32 pk2(float lo, float hi) {
    bf16x2 v; v[0] = (__bf16)lo; v[1] = (__bf16)hi;
    return __builtin_bit_cast(u32, v);
}
__device__ __forceinline__ float bf2f(u16 b) {
    u32 u = ((u32)b) << 16;
    return __builtin_bit_cast(float, u);
}
// no inline-asm exp (R6 lesson: unscheduled TRANS hazard -> nondeterminism)
__device__ __forceinline__ float exp2_fast(float x) {
#if __has_builtin(__builtin_amdgcn_exp2f)
    return __builtin_amdgcn_exp2f(x);
#else
    return exp2f(x);
#endif
}
__device__ __forceinline__ f32x4 mfma16(short8 a, short8 b, f32x4 c) {
    return __builtin_amdgcn_mfma_f32_16x16x32_bf16(a, b, c, 0, 0, 0);
}
__device__ __forceinline__ f32x16 mfma32(short8 a, short8 b, f32x16 c) {
    return __builtin_amdgcn_mfma_f32_32x32x16_bf16(a, b, c, 0, 0, 0);
}

// ---------------------------------------------------------------------------
// prep: x->bf16 convert + both weight transpose-converts.
// blocks [0,1024): conv x; [1024,1216): w_qkv^T; [1216,1280): w_out^T.
// ---------------------------------------------------------------------------
__global__ __launch_bounds__(256) void prep(const float* __restrict__ x,
                                            const float* __restrict__ wqkv,
                                            const float* __restrict__ wout,
                                            u16* __restrict__ x_bf,
                                            u16* __restrict__ wqkvT,
                                            u16* __restrict__ woutT) {
    __shared__ float T[64][65];
    const int t = threadIdx.x;
    const int bb = blockIdx.x;
    if (bb < 1024) {
        int i = (bb * 256 + t) * 8;
        float4 a = *(const float4*)&x[i];
        float4 b = *(const float4*)&x[i + 4];
        bf16x8 v;
        v[0] = (__bf16)a.x; v[1] = (__bf16)a.y; v[2] = (__bf16)a.z; v[3] = (__bf16)a.w;
        v[4] = (__bf16)b.x; v[5] = (__bf16)b.y; v[6] = (__bf16)b.z; v[7] = (__bf16)b.w;
        *(short8*)&x_bf[i] = __builtin_bit_cast(short8, v);
        return;
    }
    const float* in; u16* outp; int K, N, n0, k0;
    if (bb < 1216) {
        int bid = bb - 1024;
        in = wqkv; outp = wqkvT; K = 512; N = 1536;
        n0 = (bid % 24) * 64; k0 = (bid / 24) * 64;
    } else {
        int bid = bb - 1216;
        in = wout; outp = woutT; K = 512; N = 512;
        n0 = (bid % 8) * 64; k0 = (bid / 8) * 64;
    }
    #pragma unroll
    for (int rep = 0; rep < 4; ++rep) {
        int r = rep * 16 + (t >> 4), c = (t & 15) * 4;
        float4 v = *(const float4*)&in[(size_t)(k0 + r) * N + n0 + c];
        T[r][c + 0] = v.x; T[r][c + 1] = v.y; T[r][c + 2] = v.z; T[r][c + 3] = v.w;
    }
    __syncthreads();
    const int nl = t >> 2, kb = (t & 3) * 16;
    bf16x8 s0, s1;
    #pragma unroll
    for (int e = 0; e < 8; ++e) s0[e] = (__bf16)T[kb + e][nl];
    #pragma unroll
    for (int e = 0; e < 8; ++e) s1[e] = (__bf16)T[kb + 8 + e][nl];
    *(short8*)&outp[(size_t)(n0 + nl) * K + k0 + kb]     = __builtin_bit_cast(short8, s0);
    *(short8*)&outp[(size_t)(n0 + nl) * K + k0 + kb + 8] = __builtin_bit_cast(short8, s1);
}

// ---------------------------------------------------------------------------
// GEMM qkv: BM=128 x BN=64, BK=64, 1D grid 768 XCD-chunked.
// v path writes C^T -> vT[b,h,d,n].
// ---------------------------------------------------------------------------
__global__ __launch_bounds__(256) void gemm_qkv_mfma(const u16* __restrict__ xb,
                                                     const u16* __restrict__ wT,
                                                     u16* __restrict__ qb,
                                                     u16* __restrict__ kb,
                                                     u16* __restrict__ vT) {
    __shared__ u16 As[128][72];
    __shared__ u16 Bs[64][72];
    const int t = threadIdx.x, lane = t & 63, w = t >> 6;
    const int wm = w >> 1, wn = w & 1;
    const int l15 = lane & 15, l4 = lane >> 4;
    const int bid = blockIdx.x;
    const int swz = (bid & 7) * 96 + (bid >> 3);      // 768 = 8*96, bijective
    const int j0 = (swz % 24) * 64, i0 = (swz / 24) * 128;
    const int which = j0 / 512;           // 0=q 1=k 2=v (uniform per block)
    const int b = i0 >> 10;

    f32x4 acc[8];
    #pragma unroll
    for (int i = 0; i < 8; ++i) acc[i] = (f32x4){0.f, 0.f, 0.f, 0.f};

    const int arow0 = t >> 2, c16 = (t & 3) * 16;

    short8 ra[4], rb2[2];
    #pragma unroll
    for (int rep = 0; rep < 2; ++rep)
        #pragma unroll
        for (int q = 0; q < 2; ++q)
            ra[rep * 2 + q] = *(const short8*)&xb[(size_t)(i0 + rep * 64 + arow0) * 512 + c16 + q * 8];
    #pragma unroll
    for (int q = 0; q < 2; ++q)
        rb2[q] = *(const short8*)&wT[(size_t)(j0 + arow0) * 512 + c16 + q * 8];

    for (int kt = 0; kt < 8; ++kt) {
        __syncthreads();
        #pragma unroll
        for (int rep = 0; rep < 2; ++rep)
            #pragma unroll
            for (int q = 0; q < 2; ++q)
                *(short8*)&As[rep * 64 + arow0][c16 + q * 8] = ra[rep * 2 + q];
        #pragma unroll
        for (int q = 0; q < 2; ++q)
            *(short8*)&Bs[arow0][c16 + q * 8] = rb2[q];
        __syncthreads();
        if (kt < 7) {
            int k0 = (kt + 1) * 64;
            #pragma unroll
            for (int rep = 0; rep < 2; ++rep)
                #pragma unroll
                for (int q = 0; q < 2; ++q)
                    ra[rep * 2 + q] = *(const short8*)&xb[(size_t)(i0 + rep * 64 + arow0) * 512 + k0 + c16 + q * 8];
            #pragma unroll
            for (int q = 0; q < 2; ++q)
                rb2[q] = *(const short8*)&wT[(size_t)(j0 + arow0) * 512 + k0 + c16 + q * 8];
        }
        #pragma unroll
        for (int ks = 0; ks < 2; ++ks) {
            if (which < 2) {
                short8 af[4], bf[2];
                #pragma unroll
                for (int m = 0; m < 4; ++m)
                    af[m] = *(const short8*)&As[wm * 64 + m * 16 + l15][ks * 32 + l4 * 8];
                #pragma unroll
                for (int n = 0; n < 2; ++n)
                    bf[n] = *(const short8*)&Bs[wn * 32 + n * 16 + l15][ks * 32 + l4 * 8];
                #pragma unroll
                for (int m = 0; m < 4; ++m)
                    #pragma unroll
                    for (int n = 0; n < 2; ++n)
                        acc[m * 2 + n] = mfma16(af[m], bf[n], acc[m * 2 + n]);
            } else {
                short8 af[2], bf[4];
                #pragma unroll
                for (int mj = 0; mj < 2; ++mj)
                    af[mj] = *(const short8*)&Bs[wn * 32 + mj * 16 + l15][ks * 32 + l4 * 8];
                #pragma unroll
                for (int ni = 0; ni < 4; ++ni)
                    bf[ni] = *(const short8*)&As[wm * 64 + ni * 16 + l15][ks * 32 + l4 * 8];
                #pragma unroll
                for (int mj = 0; mj < 2; ++mj)
                    #pragma unroll
                    for (int ni = 0; ni < 4; ++ni)
                        acc[mj * 4 + ni] = mfma16(af[mj], bf[ni], acc[mj * 4 + ni]);
            }
        }
    }

    if (which < 2) {
        u16* dst = (which == 0) ? qb : kb;
        const int h = (j0 & 511) >> 6;
        #pragma unroll
        for (int m = 0; m < 4; ++m)
            #pragma unroll
            for (int n = 0; n < 2; ++n) {
                int d = wn * 32 + n * 16 + l15;
                #pragma unroll
                for (int r = 0; r < 4; ++r) {
                    int tok = i0 + wm * 64 + m * 16 + l4 * 4 + r;
                    dst[(((size_t)(b * HEADS + h)) * NSEQ + (tok & 1023)) * DHEAD + d] =
                        f2bf(acc[m * 2 + n][r]);
                }
            }
    } else {
        const int h = (j0 - 1024) >> 6;
        #pragma unroll
        for (int mj = 0; mj < 2; ++mj)
            #pragma unroll
            for (int ni = 0; ni < 4; ++ni) {
                int tok = i0 + wm * 64 + ni * 16 + l15;
                #pragma unroll
                for (int r = 0; r < 4; ++r) {
                    int d = wn * 32 + mj * 16 + l4 * 4 + r;
                    vT[(((size_t)(b * HEADS + h)) * DHEAD + d) * NSEQ + (tok & 1023)] =
                        f2bf(acc[mj * 4 + ni][r]);
                }
            }
    }
}

// ---------------------------------------------------------------------------
// Flash attention (R15-exact, best measured 61.67us): double-buffered
// pipeline, 1 barrier/jt, Q in registers, bf16 Sd, XCD-chunked swizzle,
// direct scalar O-stores.
// ---------------------------------------------------------------------------
__global__ __launch_bounds__(256, 2) void attn_mfma(const u16* __restrict__ qb,
                                                    const u16* __restrict__ kb,
                                                    const u16* __restrict__ vT,
                                                    const float* __restrict__ spd,
                                                    const float* __restrict__ head_keep,
                                                    u16* __restrict__ ab) {
    __shared__ u16 Kd[2][64][72];
    __shared__ u16 Vd[2][64][72];
    __shared__ u16 Sd[2][128][66];   // bf16 spd * log2e

    const int t = threadIdx.x, lane = t & 63, w = t >> 6;
    const int hi = lane >> 5, li = lane & 31;
    const int bid = blockIdx.x;
    const int swz = (bid & 7) * 32 + (bid >> 3);   // 256 = 8*32, bijective
    const int bh = swz >> 3, it = swz & 7;
    const int b = bh >> 3, h = bh & 7;
    const int i0 = it * 128;

    const u16* qh = qb + (size_t)bh * NSEQ * DHEAD;
    const u16* kh = kb + (size_t)bh * NSEQ * DHEAD;
    const u16* vh = vT + (size_t)bh * DHEAD * NSEQ;
    const float* sp = spd + (size_t)bh * NSEQ * NSEQ;

    // Q fragments in registers: lane (w,hi,li) needs row w*32+li only.
    short8 qreg[4];
    #pragma unroll
    for (int ds = 0; ds < 4; ++ds)
        qreg[ds] = *(const short8*)&qh[(size_t)(i0 + w * 32 + li) * DHEAD + ds * 16 + hi * 8];

    const int krow = t >> 3, kc8 = (t & 7) * 8;
    const int srow = t >> 4, sc = (t & 15) * 4;

    short8 rk[2], rv[2];
    float4 rs[8];
    // tile 0 load + stage into buf0
    #pragma unroll
    for (int rep = 0; rep < 2; ++rep) {
        rk[rep] = *(const short8*)&kh[(size_t)(rep * 32 + krow) * DHEAD + kc8];
        rv[rep] = *(const short8*)&vh[(size_t)(rep * 32 + krow) * NSEQ + kc8];
    }
    #pragma unroll
    for (int rep = 0; rep < 8; ++rep)
        rs[rep] = *(const float4*)&sp[(size_t)(i0 + rep * 16 + srow) * NSEQ + sc];
    #pragma unroll
    for (int rep = 0; rep < 2; ++rep) {
        *(short8*)&Kd[0][rep * 32 + krow][kc8] = rk[rep];
        *(short8*)&Vd[0][rep * 32 + krow][kc8] = rv[rep];
    }
    #pragma unroll
    for (int rep = 0; rep < 8; ++rep) {
        int rrow = rep * 16 + srow;
        *(u32*)&Sd[0][rrow][sc]     = pk2(rs[rep].x * LOG2E, rs[rep].y * LOG2E);
        *(u32*)&Sd[0][rrow][sc + 2] = pk2(rs[rep].z * LOG2E, rs[rep].w * LOG2E);
    }
    // issue tile-1 loads (fly across the barrier and iteration-0 compute)
    #pragma unroll
    for (int rep = 0; rep < 2; ++rep) {
        rk[rep] = *(const short8*)&kh[(size_t)(64 + rep * 32 + krow) * DHEAD + kc8];
        rv[rep] = *(const short8*)&vh[(size_t)(rep * 32 + krow) * NSEQ + 64 + kc8];
    }
    #pragma unroll
    for (int rep = 0; rep < 8; ++rep)
        rs[rep] = *(const float4*)&sp[(size_t)(i0 + rep * 16 + srow) * NSEQ + 64 + sc];
    __syncthreads();

    float m_s = -1e30f, l_s = 0.f;
    f32x16 o0 = {}, o1 = {};
    #pragma unroll
    for (int r = 0; r < 16; ++r) { o0[r] = 0.f; o1[r] = 0.f; }

    for (int jt = 0; jt < 16; ++jt) {
        const int cur = jt & 1;

        // ---- compute tile jt from buf[cur] ----
        f32x16 s2[2];
        #pragma unroll
        for (int kg = 0; kg < 2; ++kg) {
            #pragma unroll
            for (int r = 0; r < 16; ++r) s2[kg][r] = 0.f;
            #pragma unroll
            for (int ds = 0; ds < 4; ++ds) {
                short8 ak = *(const short8*)&Kd[cur][kg * 32 + li][ds * 16 + hi * 8];
                s2[kg] = mfma32(ak, qreg[ds], s2[kg]);
            }
        }

        float p2[32];
        #pragma unroll
        for (int kg = 0; kg < 2; ++kg)
            #pragma unroll
            for (int r = 0; r < 16; ++r) {
                int key = kg * 32 + (r & 3) + 8 * (r >> 2) + 4 * hi;
                p2[kg * 16 + r] = fmaf(s2[kg][r], SCALE * LOG2E,
                                       bf2f(Sd[cur][w * 32 + li][key]));
            }
        float m16[16];
        #pragma unroll
        for (int r = 0; r < 16; ++r) m16[r] = fmaxf(p2[r], p2[r + 16]);
        float m8v[8];
        #pragma unroll
        for (int r = 0; r < 8; ++r) m8v[r] = fmaxf(m16[r], m16[r + 8]);
        float m4v[4];
        #pragma unroll
        for (int r = 0; r < 4; ++r) m4v[r] = fmaxf(m8v[r], m8v[r + 4]);
        float pmax = fmaxf(fmaxf(m4v[0], m4v[1]), fmaxf(m4v[2], m4v[3]));
        pmax = fmaxf(pmax, __shfl_xor(pmax, 32));

        if (!__all(pmax <= m_s + 12.0f)) {
            float mnew = fmaxf(m_s, pmax);
            float fac = exp2_fast(m_s - mnew);
            m_s = mnew;
            l_s *= fac;
            #pragma unroll
            for (int r = 0; r < 16; ++r) {
                int ip = (r & 3) + 8 * (r >> 2) + 4 * hi;
                float fr = __shfl(fac, ip);
                o0[r] *= fr; o1[r] *= fr;
            }
        }

        float sa0 = 0.f, sa1 = 0.f, sa2 = 0.f, sa3 = 0.f;
        #pragma unroll
        for (int r = 0; r < 32; r += 4) {
            p2[r + 0] = exp2_fast(p2[r + 0] - m_s); sa0 += p2[r + 0];
            p2[r + 1] = exp2_fast(p2[r + 1] - m_s); sa1 += p2[r + 1];
            p2[r + 2] = exp2_fast(p2[r + 2] - m_s); sa2 += p2[r + 2];
            p2[r + 3] = exp2_fast(p2[r + 3] - m_s); sa3 += p2[r + 3];
        }
        float rsum = (sa0 + sa1) + (sa2 + sa3);
        rsum += __shfl_xor(rsum, 32);
        l_s += rsum;

        short8 pf[4];
        #pragma unroll
        for (int ks = 0; ks < 4; ++ks) {
            int rb = (ks >> 1) * 16 + (ks & 1) * 8;
            u32 a0 = pk2(p2[rb + 0], p2[rb + 1]);
            u32 a1 = pk2(p2[rb + 2], p2[rb + 3]);
            u32 a2 = pk2(p2[rb + 4], p2[rb + 5]);
            u32 a3 = pk2(p2[rb + 6], p2[rb + 7]);
            u32 x0 = (u32)__shfl_xor((int)a0, 32);
            u32 x1 = (u32)__shfl_xor((int)a1, 32);
            u32 x2 = (u32)__shfl_xor((int)a2, 32);
            u32 x3 = (u32)__shfl_xor((int)a3, 32);
            union { u32 u[4]; short8 v; } c4;
            c4.u[0] = hi ? x2 : a0;
            c4.u[1] = hi ? x3 : a1;
            c4.u[2] = hi ? a2 : x0;
            c4.u[3] = hi ? a3 : x1;
            pf[ks] = c4.v;
        }

        #pragma unroll
        for (int ks = 0; ks < 4; ++ks) {
            short8 v0f = *(const short8*)&Vd[cur][li][ks * 16 + hi * 8];
            short8 v1f = *(const short8*)&Vd[cur][32 + li][ks * 16 + hi * 8];
            o0 = mfma32(pf[ks], v0f, o0);
            o1 = mfma32(pf[ks], v1f, o1);
        }

        // ---- stage tile jt+1 into buf[cur^1]; issue tile jt+2 loads ----
        if (jt < 15) {
            const int nxt = cur ^ 1;
            #pragma unroll
            for (int rep = 0; rep < 2; ++rep) {
                *(short8*)&Kd[nxt][rep * 32 + krow][kc8] = rk[rep];
                *(short8*)&Vd[nxt][rep * 32 + krow][kc8] = rv[rep];
            }
            #pragma unroll
            for (int rep = 0; rep < 8; ++rep) {
                int rrow = rep * 16 + srow;
                *(u32*)&Sd[nxt][rrow][sc]     = pk2(rs[rep].x * LOG2E, rs[rep].y * LOG2E);
                *(u32*)&Sd[nxt][rrow][sc + 2] = pk2(rs[rep].z * LOG2E, rs[rep].w * LOG2E);
            }
            if (jt < 14) {
                int j0n = (jt + 2) * 64;
                #pragma unroll
                for (int rep = 0; rep < 2; ++rep) {
                    rk[rep] = *(const short8*)&kh[(size_t)(j0n + rep * 32 + krow) * DHEAD + kc8];
                    rv[rep] = *(const short8*)&vh[(size_t)(rep * 32 + krow) * NSEQ + j0n + kc8];
                }
                #pragma unroll
                for (int rep = 0; rep < 8; ++rep)
                    rs[rep] = *(const float4*)&sp[(size_t)(i0 + rep * 16 + srow) * NSEQ + j0n + sc];
            }
            __syncthreads();
        }
    }

    // epilogue (R15-exact)
    float ksum = 0.f;
    #pragma unroll
    for (int i = 0; i < HEADS; ++i) ksum += head_keep[i];
    const float hscale = head_keep[h] * (float)HEADS / ksum;
    const float inv = hscale / l_s;
    #pragma unroll
    for (int r = 0; r < 16; ++r) {
        int ip = (r & 3) + 8 * (r >> 2) + 4 * hi;
        float invr = __shfl(inv, ip);
        int tok = i0 + w * 32 + ip;
        size_t base = ((size_t)(b * NSEQ) + tok) * 512 + h * DHEAD;
        ab[base + li]      = f2bf(o0[r] * invr);
        ab[base + 32 + li] = f2bf(o1[r] * invr);
    }
}

// ---------------------------------------------------------------------------
// GEMM out: BM=64 x BN=64, BK=64, 1D grid 512 XCD-chunked.
// ---------------------------------------------------------------------------
__global__ __launch_bounds__(256) void gemm_out_mfma(const u16* __restrict__ abuf,
                                                     const u16* __restrict__ wT,
                                                     const float* __restrict__ bias,
                                                     float* __restrict__ out) {
    __shared__ u16 As[64][72];
    __shared__ u16 Bs[64][72];
    const int t = threadIdx.x, lane = t & 63, w = t >> 6;
    const int wm = w >> 1, wn = w & 1;
    const int l15 = lane & 15, l4 = lane >> 4;
    const int bid = blockIdx.x;
    const int swz = (bid & 7) * 64 + (bid >> 3);      // 512 = 8*64, bijective
    const int j0 = (swz % 8) * 64, i0 = (swz / 8) * 64;

    f32x4 acc[2][2];
    #pragma unroll
    for (int m = 0; m < 2; ++m)
        #pragma unroll
        for (int n = 0; n < 2; ++n) acc[m][n] = (f32x4){0.f, 0.f, 0.f, 0.f};

    const int row0 = t >> 2, c16 = (t & 3) * 16;
    short8 rav[2], rbv[2];
    #pragma unroll
    for (int q = 0; q < 2; ++q) {
        rav[q] = *(const short8*)&abuf[(size_t)(i0 + row0) * 512 + c16 + q * 8];
        rbv[q] = *(const short8*)&wT[(size_t)(j0 + row0) * 512 + c16 + q * 8];
    }

    for (int kt = 0; kt < 8; ++kt) {
        __syncthreads();
        #pragma unroll
        for (int q = 0; q < 2; ++q) {
            *(short8*)&As[row0][c16 + q * 8] = rav[q];
            *(short8*)&Bs[row0][c16 + q * 8] = rbv[q];
        }
        __syncthreads();
        if (kt < 7) {
            int k0 = (kt + 1) * 64;
            #pragma unroll
            for (int q = 0; q < 2; ++q) {
                rav[q] = *(const short8*)&abuf[(size_t)(i0 + row0) * 512 + k0 + c16 + q * 8];
                rbv[q] = *(const short8*)&wT[(size_t)(j0 + row0) * 512 + k0 + c16 + q * 8];
            }
        }
        #pragma unroll
        for (int ks = 0; ks < 2; ++ks) {
            short8 af[2], bf[2];
            #pragma unroll
            for (int m = 0; m < 2; ++m)
                af[m] = *(const short8*)&As[wm * 32 + m * 16 + l15][ks * 32 + l4 * 8];
            #pragma unroll
            for (int n = 0; n < 2; ++n)
                bf[n] = *(const short8*)&Bs[wn * 32 + n * 16 + l15][ks * 32 + l4 * 8];
            #pragma unroll
            for (int m = 0; m < 2; ++m)
                #pragma unroll
                for (int n = 0; n < 2; ++n)
                    acc[m][n] = mfma16(af[m], bf[n], acc[m][n]);
        }
    }

    #pragma unroll
    for (int m = 0; m < 2; ++m)
        #pragma unroll
        for (int n = 0; n < 2; ++n) {
            int col = j0 + wn * 32 + n * 16 + l15;
            float bb = bias[col];
            #pragma unroll
            for (int r = 0; r < 4; ++r) {
                int row = i0 + wm * 32 + m * 16 + l4 * 4 + r;
                out[(size_t)row * 512 + col] = acc[m][n][r] + bb;
            }
        }
}

extern "C" void kernel_launch(void* const* d_in, const int* in_sizes, int n_in,
                              void* d_out, int out_size, void* d_ws, size_t ws_size,
                              hipStream_t stream) {
    const float* x         = (const float*)d_in[0];
    const float* spd       = (const float*)d_in[1];
    const float* head_keep = (const float*)d_in[2];
    const float* w_qkv     = (const float*)d_in[3];
    const float* w_out     = (const float*)d_in[4];
    const float* b_out     = (const float*)d_in[5];
    float* out = (float*)d_out;

    char* ws = (char*)d_ws;
    u16* x_bf   = (u16*)(ws);                       // 4096*512
    u16* wqkvT  = (u16*)(ws + (4u << 20));          // 1536*512
    u16* woutT  = (u16*)(ws + (4u << 20) + 1572864);// 512*512
    u16* qb     = (u16*)(ws + (6u << 20));          // 32*1024*64
    u16* kb     = (u16*)(ws + (10u << 20));
    u16* vT     = (u16*)(ws + (14u << 20));
    u16* ab     = (u16*)(ws + (18u << 20));         // 4096*512

    prep<<<1280, 256, 0, stream>>>(x, w_qkv, w_out, x_bf, wqkvT, woutT);
    gemm_qkv_mfma<<<768, 256, 0, stream>>>(x_bf, wqkvT, qb, kb, vT);
    attn_mfma<<<256, 256, 0, stream>>>(qb, kb, vT, spd, head_keep, ab);
    gemm_out_mfma<<<512, 256, 0, stream>>>(ab, woutT, b_out, out);
}